// Round 1
// baseline (52.374 us; speedup 1.0000x reference)
//
#include <hip/hip_runtime.h>

// out[i] = 2 * x[i], N = 100 fp32. Pure launch-overhead regime:
// 800 B total traffic -> single block, one thread per element.
__global__ void Repro_10806137717294_kernel(const float* __restrict__ x,
                                            float* __restrict__ out,
                                            int n) {
    int i = blockIdx.x * blockDim.x + threadIdx.x;
    if (i < n) {
        out[i] = 2.0f * x[i];
    }
}

extern "C" void kernel_launch(void* const* d_in, const int* in_sizes, int n_in,
                              void* d_out, int out_size, void* d_ws, size_t ws_size,
                              hipStream_t stream) {
    const float* x = (const float*)d_in[0];
    float* out = (float*)d_out;
    int n = out_size;  // 100
    // One block of 128 threads (2 waves) covers all 100 elements.
    Repro_10806137717294_kernel<<<1, 128, 0, stream>>>(x, out, n);
}